// Round 1
// 658.859 us; speedup vs baseline: 1.0711x; 1.0711x over previous
//
#include <hip/hip_runtime.h>
#include <hip/hip_bf16.h>

#define BB 2
#define TT 1024
#define HIDD 4096
#define NH 32
#define DN 128
#define DR 64
#define DVV 128
#define DQK 192
#define QR 1536
#define KVR 512
#define MTOK (BB*TT)
#define EPSF 1e-6f
#define SCALEF 0.07216878364870322f  // 192^-0.5

typedef unsigned short u16;
using bfrag = __attribute__((ext_vector_type(8))) short;   // 8 bf16 = 4 VGPRs
using f4 = __attribute__((ext_vector_type(4))) float;

__device__ __forceinline__ float bf2f(u16 u){
    union { unsigned int i; float f; } v; v.i = ((unsigned int)u) << 16; return v.f;
}
__device__ __forceinline__ u16 f2bf(float f){
    union { float f; unsigned int i; } v; v.f = f;
    unsigned int r = v.i + 0x7fffu + ((v.i >> 16) & 1u);
    return (u16)(r >> 16);
}
__device__ __forceinline__ void async16(const void* g, void* l){
    __builtin_amdgcn_global_load_lds((const __attribute__((address_space(1))) void*)g,
                                     (__attribute__((address_space(3))) void*)l, 16, 0, 0);
}

// ---------------- fp32 -> bf16 elementwise (n divisible by 4) ----------------
__global__ __launch_bounds__(256) void cvt_k(const float* __restrict__ in,
                                             u16* __restrict__ out, int n)
{
    int i = (blockIdx.x * 256 + threadIdx.x) * 4;
    if (i >= n) return;
    float4 v = *(const float4*)(in + i);
    ushort4 o = make_ushort4(f2bf(v.x), f2bf(v.y), f2bf(v.z), f2bf(v.w));
    *(ushort4*)(out + i) = o;
}

// ---------------- transpose+convert: W fp32 [Kd,Nd] -> Wt bf16 [Nd,Kd] ----------------
__global__ __launch_bounds__(256) void transpose_cvt(
    const float* __restrict__ W, u16* __restrict__ Wt, int Kd, int Nd)
{
    __shared__ u16 S[32][33];
    const int n0 = blockIdx.x * 32, k0 = blockIdx.y * 32;
    const int tx = threadIdx.x & 31, ty = threadIdx.x >> 5;  // ty 0..7
    #pragma unroll
    for (int i = 0; i < 4; ++i)
        S[ty + 8 * i][tx] = f2bf(W[(size_t)(k0 + ty + 8 * i) * Nd + n0 + tx]);
    __syncthreads();
    #pragma unroll
    for (int i = 0; i < 4; ++i)
        Wt[(size_t)(n0 + ty + 8 * i) * Kd + k0 + tx] = S[tx][ty + 8 * i];
}

// ---------------- MFMA GEMM: C[M,N] = A[M,K] @ Bt[N,K]^T, bf16 in, fp32 acc ----------------
// BM=128, BK=32, 256 threads (4 waves). BN=128: 2x2 waves of 64x64. BN=64: 4x1 waves of 32x64.
// CMODE: 0 = bf16 C row-major; 1 = fp32 C row-major; 2 = split kv: k_nope -> C as
// KN[tok][head*128+c], v -> C2 as VT[((b*NH+head)*128+dv)*1024 + t] (transposed).
template<int BN, int CMODE>
__global__ __launch_bounds__(256) void gemm_bt(
    const u16* __restrict__ A, const u16* __restrict__ Bt, void* __restrict__ C,
    u16* __restrict__ C2, int M, int N, int K, int lda)
{
    constexpr int BM = 128, BK = 32;
    constexpr int WAVES_N = (BN == 128) ? 2 : 1;
    constexpr int WAVES_M = 4 / WAVES_N;
    constexpr int WM = BM / WAVES_M, WN = BN / WAVES_N;
    constexpr int FM = WM / 16, FN = WN / 16;
    constexpr int RPWB = BN / 4;           // B rows staged per wave
    __shared__ alignas(16) u16 As[BM * BK];
    __shared__ alignas(16) u16 Bs[BN * BK];
    const int tid = threadIdx.x, w = tid >> 6, ln = tid & 63;
    const int row0 = blockIdx.y * BM, col0 = blockIdx.x * BN;
    const int wm = w / WAVES_N, wn = w % WAVES_N;
    const int lr = ln & 15, lq = ln >> 4;

    f4 acc[FM][FN];
    #pragma unroll
    for (int i = 0; i < FM; ++i)
        #pragma unroll
        for (int j = 0; j < FN; ++j)
            acc[i][j] = (f4){0.f, 0.f, 0.f, 0.f};

    const u16* gA = A + (size_t)(row0 + w * 32 + (ln >> 2)) * lda + (ln & 3) * 8;
    const u16* gB = Bt + (size_t)(col0 + w * RPWB + (ln >> 2)) * K + (ln & 3) * 8;

    for (int k0 = 0; k0 < K; k0 += BK) {
        #pragma unroll
        for (int i = 0; i < 2; ++i)
            async16(gA + (size_t)i * 16 * lda + k0, &As[(w * 32 + i * 16) * BK]);
        #pragma unroll
        for (int i = 0; i < RPWB / 16; ++i)
            async16(gB + (size_t)i * 16 * K + k0, &Bs[(w * RPWB + i * 16) * BK]);
        __syncthreads();
        bfrag af[FM], bf[FN];
        #pragma unroll
        for (int fm = 0; fm < FM; ++fm)
            af[fm] = *(const bfrag*)&As[(wm * WM + fm * 16 + lr) * BK + lq * 8];
        #pragma unroll
        for (int fn = 0; fn < FN; ++fn)
            bf[fn] = *(const bfrag*)&Bs[(wn * WN + fn * 16 + lr) * BK + lq * 8];
        #pragma unroll
        for (int fm = 0; fm < FM; ++fm)
            #pragma unroll
            for (int fn = 0; fn < FN; ++fn)
                acc[fm][fn] = __builtin_amdgcn_mfma_f32_16x16x32_bf16(
                    af[fm], bf[fn], acc[fm][fn], 0, 0, 0);
        __syncthreads();
    }
    // C/D layout: col = lane&15, row = (lane>>4)*4 + reg   [m89/m91 verified]
    #pragma unroll
    for (int fm = 0; fm < FM; ++fm)
        #pragma unroll
        for (int fn = 0; fn < FN; ++fn) {
            const int col = col0 + wn * WN + fn * 16 + lr;
            const int rowb = row0 + wm * WM + fm * 16 + lq * 4;
            if (CMODE == 2) {
                const int head = col >> 8, within = col & 255;
                if (within < DN) {
                    #pragma unroll
                    for (int r = 0; r < 4; ++r)
                        ((u16*)C)[(size_t)(rowb + r) * (NH * DN) + head * DN + within]
                            = f2bf(acc[fm][fn][r]);
                } else {
                    ushort4 pk = make_ushort4(f2bf(acc[fm][fn][0]), f2bf(acc[fm][fn][1]),
                                              f2bf(acc[fm][fn][2]), f2bf(acc[fm][fn][3]));
                    size_t off = ((size_t)((rowb >> 10) * NH + head) * DVV + (within - DN)) * TT
                                 + (rowb & (TT - 1));
                    *(ushort4*)(C2 + off) = pk;
                }
            } else {
                #pragma unroll
                for (int r = 0; r < 4; ++r) {
                    size_t off = (size_t)(rowb + r) * N + col;
                    if (CMODE == 1) ((float*)C)[off] = acc[fm][fn][r];
                    else            ((u16*)C)[off] = f2bf(acc[fm][fn][r]);
                }
            }
        }
}

// ---------------- RMSNorm in-place on bf16 [rows x stride], first W cols, fp32 weight ------
__global__ __launch_bounds__(256) void rmsnorm_bf(
    u16* __restrict__ p, const float* __restrict__ w, int W, int stride)
{
    u16* x = p + (size_t)blockIdx.x * stride;
    __shared__ float red[256];
    float s = 0.f;
    for (int c = threadIdx.x; c < W; c += 256) { float v = bf2f(x[c]); s += v * v; }
    red[threadIdx.x] = s;
    __syncthreads();
    for (int off = 128; off > 0; off >>= 1) {
        if (threadIdx.x < off) red[threadIdx.x] += red[threadIdx.x + off];
        __syncthreads();
    }
    float scale = rsqrtf(red[0] / (float)W + EPSF);
    for (int c = threadIdx.x; c < W; c += 256)
        x[c] = f2bf(bf2f(x[c]) * scale * w[c]);
}

// ---------------- RoPE q_pe in-place: qbuf [MTOK, NH*192] bf16, pe at h*192+128 ----------------
__global__ void rope_q_k(u16* __restrict__ q, const int* __restrict__ pos)
{
    int idx = blockIdx.x * 256 + threadIdx.x;
    if (idx >= MTOK * NH * 32) return;
    int j = idx & 31, h = (idx >> 5) & 31, tok = idx >> 10;
    u16* p = q + (size_t)tok * (NH * DQK) + h * DQK + DN;
    float x1 = bf2f(p[j]), x2 = bf2f(p[j + 32]);
    float inv = __expf((float)j * -0.28782313662425572f);  // 10000^(-j/32)
    float ang = (float)pos[tok] * inv;
    float sn, cs; sincosf(ang, &sn, &cs);
    p[j] = f2bf(x1 * cs - x2 * sn);
    p[j + 32] = f2bf(x1 * sn + x2 * cs);
}

// ---------------- RoPE k_pe: kvd [MTOK,576] bf16 cols 512.. -> kpe [MTOK,64] bf16 ----------------
__global__ void rope_k_k(const u16* __restrict__ kvd, u16* __restrict__ kpe,
                         const int* __restrict__ pos)
{
    int idx = blockIdx.x * 256 + threadIdx.x;
    if (idx >= MTOK * 32) return;
    int j = idx & 31, tok = idx >> 5;
    const u16* p = kvd + (size_t)tok * 576 + KVR;
    float x1 = bf2f(p[j]), x2 = bf2f(p[j + 32]);
    float inv = __expf((float)j * -0.28782313662425572f);  // 10000^(-j/32)
    float ang = (float)pos[tok] * inv;
    float sn, cs; sincosf(ang, &sn, &cs);
    kpe[(size_t)tok * 64 + j] = f2bf(x1 * cs - x2 * sn);
    kpe[(size_t)tok * 64 + j + 32] = f2bf(x1 * sn + x2 * cs);
}

// ---------------- MFMA flash attention v3: TK=64, paired q-tiles, async dbuf K ----------------
// Block = (h, q-tile pair {x, 15-x}, b); h fastest in grid so the 8 pair-blocks sharing one
// (b,h)'s K/V are 32 apart -> same XCD L2. 4 waves, each owns 16 q-rows per pass.
// K tile [64][192] packed, double-buffered, staged with global_load_lds (per-lane global src
// pre-swizzled; 16B slot index XOR row&7 -> conflict-free ds_read_b128 in QK^T).
struct SMa {
    alignas(16) u16 Ks[2][64 * 192];   // 2 x 24576 B, swizzled
    alignas(16) u16 Ps[4][16 * 72];    // per-wave P tile, 16 q x 64 keys (stride 72)
};
struct SMb { alignas(16) u16 Ot[64 * 136]; };
union SMu { SMa a; SMb o; };

__global__ __launch_bounds__(256, 2) void attn_mfma(
    const u16* __restrict__ q, const u16* __restrict__ KN,
    const u16* __restrict__ kpe, const u16* __restrict__ VT,
    const int* __restrict__ amask, u16* __restrict__ O)
{
    __shared__ SMu sm;
    const int tid = threadIdx.x, w = tid >> 6, ln = tid & 63;
    const int lr = ln & 15, lq = ln >> 4;
    const int h = blockIdx.x, b = blockIdx.z;
    const u16* vtb = VT + (size_t)(b * NH + h) * DVV * TT;

    // async stage of one 64x192 K tile (k_nope | k_pe) into dst, XOR-swizzled.
    // 1536 16B slots = 4 waves x 6 issues x 64 lanes. Physical slot p holds logical
    // (row = p/24, col16 = (p%24) ^ (row&7)); read side applies the same XOR.
    auto stage = [&](u16* dst, int k0) {
        #pragma unroll
        for (int i = 0; i < 6; ++i) {
            const int p = (w * 6 + i) * 64 + ln;
            const int row = p / 24;
            const int c = (p - row * 24) ^ (row & 7);
            const int col = c << 3;                       // u16 col, 0..184
            const u16* src = (col < DN)
                ? KN + (size_t)(b * TT + k0 + row) * (NH * DN) + h * DN + col
                : kpe + (size_t)(b * TT + k0 + row) * 64 + (col - DN);
            async16(src, dst + (w * 6 + i) * 512);        // wave-uniform LDS base
        }
    };

    #pragma unroll
    for (int pass = 0; pass < 2; ++pass) {
        const int t = pass ? (15 - blockIdx.y) : blockIdx.y;
        const int q0 = t * 64;
        const int qg0 = q0 + w * 16 + lq * 4;

        // Q A-fragments: 6 k-steps of 32, loaded once per pass
        bfrag qf[6];
        const u16* qbase = q + (size_t)(b * TT + q0 + w * 16 + lr) * (NH * DQK) + h * DQK + lq * 8;
        #pragma unroll
        for (int ks = 0; ks < 6; ++ks) qf[ks] = *(const bfrag*)(qbase + ks * 32);

        f4 acc[8];
        #pragma unroll
        for (int i = 0; i < 8; ++i) acc[i] = (f4){0.f, 0.f, 0.f, 0.f};
        float m_i[4], l_i[4];
        #pragma unroll
        for (int r = 0; r < 4; ++r) { m_i[r] = -1e30f; l_i[r] = 0.f; }

        __syncthreads();               // all waves done with previous pass's Ot reads
        stage(sm.a.Ks[0], 0);
        __syncthreads();               // drains vmcnt(0): Ks[0] ready

        u16* cur = sm.a.Ks[0];
        u16* nxt = sm.a.Ks[1];
        const int nkt = t + 1;
        for (int kt = 0; kt < nkt; ++kt) {
            const int k0 = kt * 64;

            // ---- vmem issue order matters (vmcnt is in-order): mask, V, then stage ----
            float mb[4];
            #pragma unroll
            for (int nt = 0; nt < 4; ++nt)
                mb[nt] = amask[b * TT + k0 + nt * 16 + lr] ? 0.f : -1e30f;
            bfrag vf0[8], vf1[8];
            #pragma unroll
            for (int d = 0; d < 8; ++d) {
                const u16* vrow = vtb + (size_t)(d * 16 + lr) * TT + k0 + lq * 8;
                vf0[d] = *(const bfrag*)vrow;
                vf1[d] = *(const bfrag*)(vrow + 32);
            }
            if (kt + 1 < nkt) stage(nxt, k0 + 64);   // lands by end-of-tile barrier

            // ---- S = Q K^T: 16 rows x 64 keys per wave, swizzled conflict-free reads ----
            f4 sacc[4];
            #pragma unroll
            for (int nt = 0; nt < 4; ++nt) {
                sacc[nt] = (f4){0.f, 0.f, 0.f, 0.f};
                const int r_ = nt * 16 + lr;
                const u16* kr = cur + r_ * 192;
                const int sw = r_ & 7;
                #pragma unroll
                for (int ks = 0; ks < 6; ++ks) {
                    bfrag kf = *(const bfrag*)(kr + (((ks * 4 + lq) ^ sw) << 3));
                    sacc[nt] = __builtin_amdgcn_mfma_f32_16x16x32_bf16(qf[ks], kf, sacc[nt], 0, 0, 0);
                }
            }

            // ---- online softmax (C layout: key = k0+nt*16+lr, q-row = qg0+r) ----
            float s[4][4];
            #pragma unroll
            for (int nt = 0; nt < 4; ++nt) {
                const int keyg = k0 + nt * 16 + lr;
                #pragma unroll
                for (int r = 0; r < 4; ++r) {
                    float v = sacc[nt][r] * SCALEF + mb[nt];
                    s[nt][r] = (keyg <= qg0 + r) ? v : -1e30f;
                }
            }
            #pragma unroll
            for (int r = 0; r < 4; ++r) {
                float tm = fmaxf(fmaxf(s[0][r], s[1][r]), fmaxf(s[2][r], s[3][r]));
                tm = fmaxf(tm, __shfl_xor(tm, 1));
                tm = fmaxf(tm, __shfl_xor(tm, 2));
                tm = fmaxf(tm, __shfl_xor(tm, 4));
                tm = fmaxf(tm, __shfl_xor(tm, 8));
                float m_new = fmaxf(m_i[r], tm);
                float alpha = __expf(m_i[r] - m_new);
                float p0 = __expf(s[0][r] - m_new);
                float p1 = __expf(s[1][r] - m_new);
                float p2 = __expf(s[2][r] - m_new);
                float p3 = __expf(s[3][r] - m_new);
                float rs = (p0 + p1) + (p2 + p3);
                rs += __shfl_xor(rs, 1);
                rs += __shfl_xor(rs, 2);
                rs += __shfl_xor(rs, 4);
                rs += __shfl_xor(rs, 8);
                l_i[r] = l_i[r] * alpha + rs;
                m_i[r] = m_new;
                #pragma unroll
                for (int d = 0; d < 8; ++d) acc[d][r] *= alpha;
                sm.a.Ps[w][(lq * 4 + r) * 72 + lr] = f2bf(p0);
                sm.a.Ps[w][(lq * 4 + r) * 72 + 16 + lr] = f2bf(p1);
                sm.a.Ps[w][(lq * 4 + r) * 72 + 32 + lr] = f2bf(p2);
                sm.a.Ps[w][(lq * 4 + r) * 72 + 48 + lr] = f2bf(p3);
            }
            // ---- PV: A = P (16x64 as two 32-k halves), B = prefetched V^T fragments ----
            bfrag pf0 = *(const bfrag*)&sm.a.Ps[w][lr * 72 + lq * 8];
            bfrag pf1 = *(const bfrag*)&sm.a.Ps[w][lr * 72 + 32 + lq * 8];
            #pragma unroll
            for (int d = 0; d < 8; ++d) {
                acc[d] = __builtin_amdgcn_mfma_f32_16x16x32_bf16(pf0, vf0[d], acc[d], 0, 0, 0);
                acc[d] = __builtin_amdgcn_mfma_f32_16x16x32_bf16(pf1, vf1[d], acc[d], 0, 0, 0);
            }
            __syncthreads();   // drains vmcnt(0): stage(nxt) landed; all waves done with cur
            u16* tmp = cur; cur = nxt; nxt = tmp;
        }
        // epilogue: normalize, stage to LDS, coalesced store (last barrier above makes
        // the union Ks/Ps -> Ot overwrite safe)
        float inv_l[4];
        #pragma unroll
        for (int r = 0; r < 4; ++r) inv_l[r] = 1.0f / l_i[r];
        #pragma unroll
        for (int d = 0; d < 8; ++d)
            #pragma unroll
            for (int r = 0; r < 4; ++r)
                sm.o.Ot[(w * 16 + lq * 4 + r) * 136 + d * 16 + lr] = f2bf(acc[d][r] * inv_l[r]);
        __syncthreads();
        #pragma unroll
        for (int it = 0; it < 8; ++it) {
            int u = it * 256 + tid;                    // 2048 vec4 groups
            int orow = u >> 5, ocol = (u & 31) * 4;
            ushort4 o4 = *(const ushort4*)&sm.o.Ot[orow * 136 + ocol];
            *(ushort4*)&O[(size_t)(b * TT + q0 + orow) * (NH * DVV) + h * DVV + ocol] = o4;
        }
    }
}

extern "C" void kernel_launch(void* const* d_in, const int* in_sizes, int n_in,
                              void* d_out, int out_size, void* d_ws, size_t ws_size,
                              hipStream_t stream)
{
    const float* x      = (const float*)d_in[0];
    const float* wq_a   = (const float*)d_in[1];
    const float* q_nw   = (const float*)d_in[2];
    const float* wq_b   = (const float*)d_in[3];
    const float* wkv_a  = (const float*)d_in[4];
    const float* kv_nw  = (const float*)d_in[5];
    const float* wkv_b  = (const float*)d_in[6];
    const float* wo     = (const float*)d_in[7];
    const int* amask    = (const int*)d_in[8];
    const int* pos      = (const int*)d_in[9];

    u16* ws = (u16*)d_ws;
    u16* wqa_t  = ws;                                    // [1536,4096]
    u16* wqb_t  = wqa_t  + (size_t)QR * HIDD;            // [6144,1536]
    u16* wkva_t = wqb_t  + (size_t)NH * DQK * QR;        // [576,4096]
    u16* wkvb_t = wkva_t + (size_t)576 * HIDD;           // [8192,512]
    u16* wo_t   = wkvb_t + (size_t)NH * 256 * KVR;       // [4096,4096]
    u16* xb     = wo_t   + (size_t)HIDD * HIDD;          // [2048,4096]
    u16* q_down = xb     + (size_t)MTOK * HIDD;          // [2048,1536]
    u16* qbuf   = q_down + (size_t)MTOK * QR;            // [2048,6144]
    u16* kvd    = qbuf   + (size_t)MTOK * NH * DQK;      // [2048,576]
    u16* kpe    = kvd    + (size_t)MTOK * 576;           // [2048,64]
    u16* KN     = kpe    + (size_t)MTOK * 64;            // [2048,4096]
    u16* VT     = KN     + (size_t)MTOK * NH * DN;       // [64,128,1024]
    u16* Obuf   = wqa_t;  // alias: wqa_t/wqb_t dead once attn runs

    cvt_k<<<(MTOK*HIDD/4 + 255)/256, 256, 0, stream>>>(x, xb, MTOK*HIDD);
    transpose_cvt<<<dim3(QR/32, HIDD/32), 256, 0, stream>>>(wq_a, wqa_t, HIDD, QR);
    transpose_cvt<<<dim3(NH*DQK/32, QR/32), 256, 0, stream>>>(wq_b, wqb_t, QR, NH*DQK);
    transpose_cvt<<<dim3(576/32, HIDD/32), 256, 0, stream>>>(wkv_a, wkva_t, HIDD, 576);
    transpose_cvt<<<dim3(NH*256/32, KVR/32), 256, 0, stream>>>(wkv_b, wkvb_t, KVR, NH*256);
    transpose_cvt<<<dim3(HIDD/32, HIDD/32), 256, 0, stream>>>(wo, wo_t, HIDD, HIDD);

    gemm_bt<128, 0><<<dim3(QR/128, MTOK/128), 256, 0, stream>>>(
        xb, wqa_t, q_down, nullptr, MTOK, QR, HIDD, HIDD);
    gemm_bt<64, 0><<<dim3(576/64, MTOK/128), 256, 0, stream>>>(
        xb, wkva_t, kvd, nullptr, MTOK, 576, HIDD, HIDD);
    rmsnorm_bf<<<MTOK, 256, 0, stream>>>(q_down, q_nw, QR, QR);
    rmsnorm_bf<<<MTOK, 256, 0, stream>>>(kvd, kv_nw, KVR, 576);
    rope_k_k<<<(MTOK*32 + 255)/256, 256, 0, stream>>>(kvd, kpe, pos);
    gemm_bt<128, 0><<<dim3(NH*DQK/128, MTOK/128), 256, 0, stream>>>(
        q_down, wqb_t, qbuf, nullptr, MTOK, NH*DQK, QR, QR);
    gemm_bt<128, 2><<<dim3(NH*256/128, MTOK/128), 256, 0, stream>>>(
        kvd, wkvb_t, KN, VT, MTOK, NH*256, KVR, 576);
    rope_q_k<<<(MTOK*NH*32 + 255)/256, 256, 0, stream>>>(qbuf, pos);
    attn_mfma<<<dim3(NH, 8, BB), 256, 0, stream>>>(qbuf, KN, kpe, VT, amask, Obuf);
    gemm_bt<128, 1><<<dim3(HIDD/128, MTOK/128), 256, 0, stream>>>(
        Obuf, wo_t, (float*)d_out, nullptr, MTOK, HIDD, NH*DVV, NH*DVV);
}

// Round 2
// 586.199 us; speedup vs baseline: 1.2038x; 1.1240x over previous
//
#include <hip/hip_runtime.h>
#include <hip/hip_bf16.h>

#define BB 2
#define TT 1024
#define HIDD 4096
#define NH 32
#define DN 128
#define DR 64
#define DVV 128
#define DQK 192
#define QR 1536
#define KVR 512
#define MTOK (BB*TT)
#define EPSF 1e-6f
#define SCALEF 0.07216878364870322f  // 192^-0.5

typedef unsigned short u16;
using bfrag = __attribute__((ext_vector_type(8))) short;   // 8 bf16 = 4 VGPRs
using f4 = __attribute__((ext_vector_type(4))) float;

__device__ __forceinline__ float bf2f(u16 u){
    union { unsigned int i; float f; } v; v.i = ((unsigned int)u) << 16; return v.f;
}
__device__ __forceinline__ u16 f2bf(float f){
    union { float f; unsigned int i; } v; v.f = f;
    unsigned int r = v.i + 0x7fffu + ((v.i >> 16) & 1u);
    return (u16)(r >> 16);
}
__device__ __forceinline__ void async16(const void* g, void* l){
    __builtin_amdgcn_global_load_lds((const __attribute__((address_space(1))) void*)g,
                                     (__attribute__((address_space(3))) void*)l, 16, 0, 0);
}

// ---------------- fp32 -> bf16 elementwise (n divisible by 4) ----------------
__global__ __launch_bounds__(256) void cvt_k(const float* __restrict__ in,
                                             u16* __restrict__ out, int n)
{
    int i = (blockIdx.x * 256 + threadIdx.x) * 4;
    if (i >= n) return;
    float4 v = *(const float4*)(in + i);
    ushort4 o = make_ushort4(f2bf(v.x), f2bf(v.y), f2bf(v.z), f2bf(v.w));
    *(ushort4*)(out + i) = o;
}

// ---------------- transpose+convert: W fp32 [Kd,Nd] -> Wt bf16 [Nd,Kd] ----------------
__global__ __launch_bounds__(256) void transpose_cvt(
    const float* __restrict__ W, u16* __restrict__ Wt, int Kd, int Nd)
{
    __shared__ u16 S[32][33];
    const int n0 = blockIdx.x * 32, k0 = blockIdx.y * 32;
    const int tx = threadIdx.x & 31, ty = threadIdx.x >> 5;  // ty 0..7
    #pragma unroll
    for (int i = 0; i < 4; ++i)
        S[ty + 8 * i][tx] = f2bf(W[(size_t)(k0 + ty + 8 * i) * Nd + n0 + tx]);
    __syncthreads();
    #pragma unroll
    for (int i = 0; i < 4; ++i)
        Wt[(size_t)(n0 + ty + 8 * i) * Kd + k0 + tx] = S[tx][ty + 8 * i];
}

// ---------------- MFMA GEMM v2: C[M,N] = A[M,K] @ Bt[N,K]^T, bf16 in, fp32 acc -------------
// BM=128, BK=64, 256 threads (4 waves), double-buffered LDS, depth-1 async prefetch,
// one barrier per K-step. Both-sides XOR swizzle: physical 16B slot (p&7) of LDS row r
// holds logical slot (p&7)^(r&7) -> conflict-free ds_read_b128 fragment reads.
// BN=128: 2x2 waves of 64x64. BN=64: 4x1 waves of 32x64.
// CMODE: 0 = bf16 C row-major; 1 = fp32 C row-major; 2 = split kv: k_nope -> C as
// KN[tok][head*128+c], v -> C2 as VT[((b*NH+head)*128+dv)*1024 + t] (transposed).
template<int BN, int CMODE>
__global__ __launch_bounds__(256) void gemm_bt(
    const u16* __restrict__ A, const u16* __restrict__ Bt, void* __restrict__ C,
    u16* __restrict__ C2, int M, int N, int K, int lda)
{
    constexpr int BM = 128, BK = 64;
    constexpr int WAVES_N = (BN == 128) ? 2 : 1;
    constexpr int WAVES_M = 4 / WAVES_N;
    constexpr int WM = BM / WAVES_M, WN = BN / WAVES_N;
    constexpr int FM = WM / 16, FN = WN / 16;
    constexpr int AISS = (BM * BK / 8) / 256;   // global_load_lds issues per wave for A (4)
    constexpr int BISS = (BN * BK / 8) / 256;   // for B (4 or 2)
    __shared__ alignas(16) u16 As[2][BM * BK];
    __shared__ alignas(16) u16 Bs[2][BN * BK];
    const int tid = threadIdx.x, w = tid >> 6, ln = tid & 63;
    const int row0 = blockIdx.y * BM, col0 = blockIdx.x * BN;
    const int wm = w / WAVES_N, wn = w % WAVES_N;
    const int lr = ln & 15, lq = ln >> 4;
    const int sw = lr & 7;

    f4 acc[FM][FN];
    #pragma unroll
    for (int i = 0; i < FM; ++i)
        #pragma unroll
        for (int j = 0; j < FN; ++j)
            acc[i][j] = (f4){0.f, 0.f, 0.f, 0.f};

    // staging: issue i covers physical slots p = (w*ISS+i)*64 + ln; row r = p>>3 steps by 8
    // per issue so r&7 = ln>>3 is issue-invariant; swizzled source column = ((ln&7)^(ln>>3))*8.
    const int srow = ln >> 3;
    const int scol = ((ln & 7) ^ srow) * 8;
    const u16* pA = A + (size_t)(row0 + w * (AISS * 8) + srow) * lda + scol;
    const u16* pB = Bt + (size_t)(col0 + w * (BISS * 8) + srow) * K + scol;

    auto stageA = [&](int buf, int k0) {
        #pragma unroll
        for (int i = 0; i < AISS; ++i)
            async16(pA + (size_t)i * 8 * lda + k0, &As[buf][(w * AISS + i) * 512]);
    };
    auto stageB = [&](int buf, int k0) {
        #pragma unroll
        for (int i = 0; i < BISS; ++i)
            async16(pB + (size_t)i * 8 * K + k0, &Bs[buf][(w * BISS + i) * 512]);
    };

    stageA(0, 0); stageB(0, 0);
    __syncthreads();                               // drain: buf0 ready

    const int nkt = K / BK;
    int cur = 0;
    for (int kt = 0; kt < nkt; ++kt) {
        if (kt + 1 < nkt) { stageA(cur ^ 1, (kt + 1) * BK); stageB(cur ^ 1, (kt + 1) * BK); }
        #pragma unroll
        for (int ks = 0; ks < 2; ++ks) {
            const int sl = ((ks * 4 + lq) ^ sw) * 8;
            bfrag af[FM], bfr[FN];
            #pragma unroll
            for (int fm = 0; fm < FM; ++fm)
                af[fm] = *(const bfrag*)&As[cur][(wm * WM + fm * 16 + lr) * BK + sl];
            #pragma unroll
            for (int fn = 0; fn < FN; ++fn)
                bfr[fn] = *(const bfrag*)&Bs[cur][(wn * WN + fn * 16 + lr) * BK + sl];
            #pragma unroll
            for (int fm = 0; fm < FM; ++fm)
                #pragma unroll
                for (int fn = 0; fn < FN; ++fn)
                    acc[fm][fn] = __builtin_amdgcn_mfma_f32_16x16x32_bf16(
                        af[fm], bfr[fn], acc[fm][fn], 0, 0, 0);
        }
        __syncthreads();       // drains vmcnt(0): next buf staged; all waves done with cur
        cur ^= 1;
    }
    // C/D layout: col = lane&15, row = (lane>>4)*4 + reg   [m89/m91 verified]
    #pragma unroll
    for (int fm = 0; fm < FM; ++fm)
        #pragma unroll
        for (int fn = 0; fn < FN; ++fn) {
            const int col = col0 + wn * WN + fn * 16 + lr;
            const int rowb = row0 + wm * WM + fm * 16 + lq * 4;
            if (CMODE == 2) {
                const int head = col >> 8, within = col & 255;
                if (within < DN) {
                    #pragma unroll
                    for (int r = 0; r < 4; ++r)
                        ((u16*)C)[(size_t)(rowb + r) * (NH * DN) + head * DN + within]
                            = f2bf(acc[fm][fn][r]);
                } else {
                    ushort4 pk = make_ushort4(f2bf(acc[fm][fn][0]), f2bf(acc[fm][fn][1]),
                                              f2bf(acc[fm][fn][2]), f2bf(acc[fm][fn][3]));
                    size_t off = ((size_t)((rowb >> 10) * NH + head) * DVV + (within - DN)) * TT
                                 + (rowb & (TT - 1));
                    *(ushort4*)(C2 + off) = pk;
                }
            } else {
                #pragma unroll
                for (int r = 0; r < 4; ++r) {
                    size_t off = (size_t)(rowb + r) * N + col;
                    if (CMODE == 1) ((float*)C)[off] = acc[fm][fn][r];
                    else            ((u16*)C)[off] = f2bf(acc[fm][fn][r]);
                }
            }
        }
}

// ---------------- RMSNorm in-place on bf16 [rows x stride], first W cols, fp32 weight ------
__global__ __launch_bounds__(256) void rmsnorm_bf(
    u16* __restrict__ p, const float* __restrict__ w, int W, int stride)
{
    u16* x = p + (size_t)blockIdx.x * stride;
    __shared__ float red[256];
    float s = 0.f;
    for (int c = threadIdx.x; c < W; c += 256) { float v = bf2f(x[c]); s += v * v; }
    red[threadIdx.x] = s;
    __syncthreads();
    for (int off = 128; off > 0; off >>= 1) {
        if (threadIdx.x < off) red[threadIdx.x] += red[threadIdx.x + off];
        __syncthreads();
    }
    float scale = rsqrtf(red[0] / (float)W + EPSF);
    for (int c = threadIdx.x; c < W; c += 256)
        x[c] = f2bf(bf2f(x[c]) * scale * w[c]);
}

// ---------------- RoPE q_pe in-place: qbuf [MTOK, NH*192] bf16, pe at h*192+128 ----------------
__global__ void rope_q_k(u16* __restrict__ q, const int* __restrict__ pos)
{
    int idx = blockIdx.x * 256 + threadIdx.x;
    if (idx >= MTOK * NH * 32) return;
    int j = idx & 31, h = (idx >> 5) & 31, tok = idx >> 10;
    u16* p = q + (size_t)tok * (NH * DQK) + h * DQK + DN;
    float x1 = bf2f(p[j]), x2 = bf2f(p[j + 32]);
    float inv = __expf((float)j * -0.28782313662425572f);  // 10000^(-j/32)
    float ang = (float)pos[tok] * inv;
    float sn, cs; sincosf(ang, &sn, &cs);
    p[j] = f2bf(x1 * cs - x2 * sn);
    p[j + 32] = f2bf(x1 * sn + x2 * cs);
}

// ---------------- RoPE k_pe: kvd [MTOK,576] bf16 cols 512.. -> kpe [MTOK,64] bf16 ----------------
__global__ void rope_k_k(const u16* __restrict__ kvd, u16* __restrict__ kpe,
                         const int* __restrict__ pos)
{
    int idx = blockIdx.x * 256 + threadIdx.x;
    if (idx >= MTOK * 32) return;
    int j = idx & 31, tok = idx >> 5;
    const u16* p = kvd + (size_t)tok * 576 + KVR;
    float x1 = bf2f(p[j]), x2 = bf2f(p[j + 32]);
    float inv = __expf((float)j * -0.28782313662425572f);  // 10000^(-j/32)
    float ang = (float)pos[tok] * inv;
    float sn, cs; sincosf(ang, &sn, &cs);
    kpe[(size_t)tok * 64 + j] = f2bf(x1 * cs - x2 * sn);
    kpe[(size_t)tok * 64 + j + 32] = f2bf(x1 * sn + x2 * cs);
}

// ---------------- MFMA flash attention v3: TK=64, paired q-tiles, async dbuf K ----------------
// Block = (h, q-tile pair {x, 15-x}, b); h fastest in grid so the 8 pair-blocks sharing one
// (b,h)'s K/V are 32 apart -> same XCD L2. 4 waves, each owns 16 q-rows per pass.
// K tile [64][192] packed, double-buffered, staged with global_load_lds (per-lane global src
// pre-swizzled; 16B slot index XOR row&7 -> conflict-free ds_read_b128 in QK^T).
struct SMa {
    alignas(16) u16 Ks[2][64 * 192];   // 2 x 24576 B, swizzled
    alignas(16) u16 Ps[4][16 * 72];    // per-wave P tile, 16 q x 64 keys (stride 72)
};
struct SMb { alignas(16) u16 Ot[64 * 136]; };
union SMu { SMa a; SMb o; };

__global__ __launch_bounds__(256, 2) void attn_mfma(
    const u16* __restrict__ q, const u16* __restrict__ KN,
    const u16* __restrict__ kpe, const u16* __restrict__ VT,
    const int* __restrict__ amask, u16* __restrict__ O)
{
    __shared__ SMu sm;
    const int tid = threadIdx.x, w = tid >> 6, ln = tid & 63;
    const int lr = ln & 15, lq = ln >> 4;
    const int h = blockIdx.x, b = blockIdx.z;
    const u16* vtb = VT + (size_t)(b * NH + h) * DVV * TT;

    // async stage of one 64x192 K tile (k_nope | k_pe) into dst, XOR-swizzled.
    // 1536 16B slots = 4 waves x 6 issues x 64 lanes. Physical slot p holds logical
    // (row = p/24, col16 = (p%24) ^ (row&7)); read side applies the same XOR.
    auto stage = [&](u16* dst, int k0) {
        #pragma unroll
        for (int i = 0; i < 6; ++i) {
            const int p = (w * 6 + i) * 64 + ln;
            const int row = p / 24;
            const int c = (p - row * 24) ^ (row & 7);
            const int col = c << 3;                       // u16 col, 0..184
            const u16* src = (col < DN)
                ? KN + (size_t)(b * TT + k0 + row) * (NH * DN) + h * DN + col
                : kpe + (size_t)(b * TT + k0 + row) * 64 + (col - DN);
            async16(src, dst + (w * 6 + i) * 512);        // wave-uniform LDS base
        }
    };

    #pragma unroll
    for (int pass = 0; pass < 2; ++pass) {
        const int t = pass ? (15 - blockIdx.y) : blockIdx.y;
        const int q0 = t * 64;
        const int qg0 = q0 + w * 16 + lq * 4;

        // Q A-fragments: 6 k-steps of 32, loaded once per pass
        bfrag qf[6];
        const u16* qbase = q + (size_t)(b * TT + q0 + w * 16 + lr) * (NH * DQK) + h * DQK + lq * 8;
        #pragma unroll
        for (int ks = 0; ks < 6; ++ks) qf[ks] = *(const bfrag*)(qbase + ks * 32);

        f4 acc[8];
        #pragma unroll
        for (int i = 0; i < 8; ++i) acc[i] = (f4){0.f, 0.f, 0.f, 0.f};
        float m_i[4], l_i[4];
        #pragma unroll
        for (int r = 0; r < 4; ++r) { m_i[r] = -1e30f; l_i[r] = 0.f; }

        __syncthreads();               // all waves done with previous pass's Ot reads
        stage(sm.a.Ks[0], 0);
        __syncthreads();               // drains vmcnt(0): Ks[0] ready

        u16* cur = sm.a.Ks[0];
        u16* nxt = sm.a.Ks[1];
        const int nkt = t + 1;
        for (int kt = 0; kt < nkt; ++kt) {
            const int k0 = kt * 64;

            // ---- vmem issue order matters (vmcnt is in-order): mask, V, then stage ----
            float mb[4];
            #pragma unroll
            for (int nt = 0; nt < 4; ++nt)
                mb[nt] = amask[b * TT + k0 + nt * 16 + lr] ? 0.f : -1e30f;
            bfrag vf0[8], vf1[8];
            #pragma unroll
            for (int d = 0; d < 8; ++d) {
                const u16* vrow = vtb + (size_t)(d * 16 + lr) * TT + k0 + lq * 8;
                vf0[d] = *(const bfrag*)vrow;
                vf1[d] = *(const bfrag*)(vrow + 32);
            }
            if (kt + 1 < nkt) stage(nxt, k0 + 64);   // lands by end-of-tile barrier

            // ---- S = Q K^T: 16 rows x 64 keys per wave, swizzled conflict-free reads ----
            f4 sacc[4];
            #pragma unroll
            for (int nt = 0; nt < 4; ++nt) {
                sacc[nt] = (f4){0.f, 0.f, 0.f, 0.f};
                const int r_ = nt * 16 + lr;
                const u16* kr = cur + r_ * 192;
                const int sw = r_ & 7;
                #pragma unroll
                for (int ks = 0; ks < 6; ++ks) {
                    bfrag kf = *(const bfrag*)(kr + (((ks * 4 + lq) ^ sw) << 3));
                    sacc[nt] = __builtin_amdgcn_mfma_f32_16x16x32_bf16(qf[ks], kf, sacc[nt], 0, 0, 0);
                }
            }

            // ---- online softmax (C layout: key = k0+nt*16+lr, q-row = qg0+r) ----
            float s[4][4];
            #pragma unroll
            for (int nt = 0; nt < 4; ++nt) {
                const int keyg = k0 + nt * 16 + lr;
                #pragma unroll
                for (int r = 0; r < 4; ++r) {
                    float v = sacc[nt][r] * SCALEF + mb[nt];
                    s[nt][r] = (keyg <= qg0 + r) ? v : -1e30f;
                }
            }
            #pragma unroll
            for (int r = 0; r < 4; ++r) {
                float tm = fmaxf(fmaxf(s[0][r], s[1][r]), fmaxf(s[2][r], s[3][r]));
                tm = fmaxf(tm, __shfl_xor(tm, 1));
                tm = fmaxf(tm, __shfl_xor(tm, 2));
                tm = fmaxf(tm, __shfl_xor(tm, 4));
                tm = fmaxf(tm, __shfl_xor(tm, 8));
                float m_new = fmaxf(m_i[r], tm);
                float alpha = __expf(m_i[r] - m_new);
                float p0 = __expf(s[0][r] - m_new);
                float p1 = __expf(s[1][r] - m_new);
                float p2 = __expf(s[2][r] - m_new);
                float p3 = __expf(s[3][r] - m_new);
                float rs = (p0 + p1) + (p2 + p3);
                rs += __shfl_xor(rs, 1);
                rs += __shfl_xor(rs, 2);
                rs += __shfl_xor(rs, 4);
                rs += __shfl_xor(rs, 8);
                l_i[r] = l_i[r] * alpha + rs;
                m_i[r] = m_new;
                #pragma unroll
                for (int d = 0; d < 8; ++d) acc[d][r] *= alpha;
                sm.a.Ps[w][(lq * 4 + r) * 72 + lr] = f2bf(p0);
                sm.a.Ps[w][(lq * 4 + r) * 72 + 16 + lr] = f2bf(p1);
                sm.a.Ps[w][(lq * 4 + r) * 72 + 32 + lr] = f2bf(p2);
                sm.a.Ps[w][(lq * 4 + r) * 72 + 48 + lr] = f2bf(p3);
            }
            // ---- PV: A = P (16x64 as two 32-k halves), B = prefetched V^T fragments ----
            bfrag pf0 = *(const bfrag*)&sm.a.Ps[w][lr * 72 + lq * 8];
            bfrag pf1 = *(const bfrag*)&sm.a.Ps[w][lr * 72 + 32 + lq * 8];
            #pragma unroll
            for (int d = 0; d < 8; ++d) {
                acc[d] = __builtin_amdgcn_mfma_f32_16x16x32_bf16(pf0, vf0[d], acc[d], 0, 0, 0);
                acc[d] = __builtin_amdgcn_mfma_f32_16x16x32_bf16(pf1, vf1[d], acc[d], 0, 0, 0);
            }
            __syncthreads();   // drains vmcnt(0): stage(nxt) landed; all waves done with cur
            u16* tmp = cur; cur = nxt; nxt = tmp;
        }
        // epilogue: normalize, stage to LDS, coalesced store (last barrier above makes
        // the union Ks/Ps -> Ot overwrite safe)
        float inv_l[4];
        #pragma unroll
        for (int r = 0; r < 4; ++r) inv_l[r] = 1.0f / l_i[r];
        #pragma unroll
        for (int d = 0; d < 8; ++d)
            #pragma unroll
            for (int r = 0; r < 4; ++r)
                sm.o.Ot[(w * 16 + lq * 4 + r) * 136 + d * 16 + lr] = f2bf(acc[d][r] * inv_l[r]);
        __syncthreads();
        #pragma unroll
        for (int it = 0; it < 8; ++it) {
            int u = it * 256 + tid;                    // 2048 vec4 groups
            int orow = u >> 5, ocol = (u & 31) * 4;
            ushort4 o4 = *(const ushort4*)&sm.o.Ot[orow * 136 + ocol];
            *(ushort4*)&O[(size_t)(b * TT + q0 + orow) * (NH * DVV) + h * DVV + ocol] = o4;
        }
    }
}

extern "C" void kernel_launch(void* const* d_in, const int* in_sizes, int n_in,
                              void* d_out, int out_size, void* d_ws, size_t ws_size,
                              hipStream_t stream)
{
    const float* x      = (const float*)d_in[0];
    const float* wq_a   = (const float*)d_in[1];
    const float* q_nw   = (const float*)d_in[2];
    const float* wq_b   = (const float*)d_in[3];
    const float* wkv_a  = (const float*)d_in[4];
    const float* kv_nw  = (const float*)d_in[5];
    const float* wkv_b  = (const float*)d_in[6];
    const float* wo     = (const float*)d_in[7];
    const int* amask    = (const int*)d_in[8];
    const int* pos      = (const int*)d_in[9];

    u16* ws = (u16*)d_ws;
    u16* wqa_t  = ws;                                    // [1536,4096]
    u16* wqb_t  = wqa_t  + (size_t)QR * HIDD;            // [6144,1536]
    u16* wkva_t = wqb_t  + (size_t)NH * DQK * QR;        // [576,4096]
    u16* wkvb_t = wkva_t + (size_t)576 * HIDD;           // [8192,512]
    u16* wo_t   = wkvb_t + (size_t)NH * 256 * KVR;       // [4096,4096]
    u16* xb     = wo_t   + (size_t)HIDD * HIDD;          // [2048,4096]
    u16* q_down = xb     + (size_t)MTOK * HIDD;          // [2048,1536]
    u16* qbuf   = q_down + (size_t)MTOK * QR;            // [2048,6144]
    u16* kvd    = qbuf   + (size_t)MTOK * NH * DQK;      // [2048,576]
    u16* kpe    = kvd    + (size_t)MTOK * 576;           // [2048,64]
    u16* KN     = kpe    + (size_t)MTOK * 64;            // [2048,4096]
    u16* VT     = KN     + (size_t)MTOK * NH * DN;       // [64,128,1024]
    u16* Obuf   = wqa_t;  // alias: wqa_t/wqb_t dead once attn runs

    cvt_k<<<(MTOK*HIDD/4 + 255)/256, 256, 0, stream>>>(x, xb, MTOK*HIDD);
    transpose_cvt<<<dim3(QR/32, HIDD/32), 256, 0, stream>>>(wq_a, wqa_t, HIDD, QR);
    transpose_cvt<<<dim3(NH*DQK/32, QR/32), 256, 0, stream>>>(wq_b, wqb_t, QR, NH*DQK);
    transpose_cvt<<<dim3(576/32, HIDD/32), 256, 0, stream>>>(wkv_a, wkva_t, HIDD, 576);
    transpose_cvt<<<dim3(NH*256/32, KVR/32), 256, 0, stream>>>(wkv_b, wkvb_t, KVR, NH*256);
    transpose_cvt<<<dim3(HIDD/32, HIDD/32), 256, 0, stream>>>(wo, wo_t, HIDD, HIDD);

    gemm_bt<128, 0><<<dim3(QR/128, MTOK/128), 256, 0, stream>>>(
        xb, wqa_t, q_down, nullptr, MTOK, QR, HIDD, HIDD);
    gemm_bt<64, 0><<<dim3(576/64, MTOK/128), 256, 0, stream>>>(
        xb, wkva_t, kvd, nullptr, MTOK, 576, HIDD, HIDD);
    rmsnorm_bf<<<MTOK, 256, 0, stream>>>(q_down, q_nw, QR, QR);
    rmsnorm_bf<<<MTOK, 256, 0, stream>>>(kvd, kv_nw, KVR, 576);
    rope_k_k<<<(MTOK*32 + 255)/256, 256, 0, stream>>>(kvd, kpe, pos);
    gemm_bt<128, 0><<<dim3(NH*DQK/128, MTOK/128), 256, 0, stream>>>(
        q_down, wqb_t, qbuf, nullptr, MTOK, NH*DQK, QR, QR);
    gemm_bt<128, 2><<<dim3(NH*256/128, MTOK/128), 256, 0, stream>>>(
        kvd, wkvb_t, KN, VT, MTOK, NH*256, KVR, 576);
    rope_q_k<<<(MTOK*NH*32 + 255)/256, 256, 0, stream>>>(qbuf, pos);
    attn_mfma<<<dim3(NH, 8, BB), 256, 0, stream>>>(qbuf, KN, kpe, VT, amask, Obuf);
    gemm_bt<128, 1><<<dim3(HIDD/128, MTOK/128), 256, 0, stream>>>(
        Obuf, wo_t, (float*)d_out, nullptr, MTOK, HIDD, NH*DVV, NH*DVV);
}